// Round 35
// baseline (91.082 us; speedup 1.0000x reference)
//
#include <hip/hip_runtime.h>
#include <math.h>

#define B_ 8192

typedef __attribute__((ext_vector_type(8))) short short8;
typedef __attribute__((ext_vector_type(4))) float f32x4;

// ---------------- persistent device buffers (rewritten every call) ----------------
// ALL GEMM B-matrices stored wave-coalesced: [tile][kkc][r(16)][k^(32)] so one wave
// load = one contiguous 1KB block (lane addr = base + l15*64B + lhi*16B).
__device__ unsigned short g_w1p[51200];                    // conv1 [kc25][ng4][r][k^], /maxv, HI-ONLY
__device__ unsigned short g_w2p[36864];                    // conv2 [kc9*ks2*nt4][r][k^], HI-ONLY
__device__ unsigned short g_fc1hi[32768], g_fc1lo[32768];  // fc1   [tn8][kk8][r][k^] (k'=pos*64+oc)
__device__ unsigned short g_enchi[16384], g_enclo[16384];  // enc   [tn8][kk4][r][k^]
__device__ unsigned short g_crp[131072];                   // critic[tn64][kk4][r][k^], HI-ONLY
__device__ unsigned short g_acp[65536];                    // actor [tn32][kk4][r][k^], HI-ONLY
__device__ unsigned short g_qWp[8192];                     // qW^T  [ck16][e16][k^32], HI-ONLY
// activations
__device__ unsigned short g_ACT1hi[8192*1024];             // conv1 out [s][pos*64+oc], HI-ONLY

__device__ __forceinline__ unsigned short f2bf(float v){
    unsigned u = __builtin_bit_cast(unsigned, v);
    unsigned r = (u + 0x7fffu + ((u >> 16) & 1u)) >> 16;   // RN-even (finite inputs)
    return (unsigned short)r;
}
__device__ __forceinline__ float bf2f(unsigned short h){
    unsigned u = ((unsigned)h) << 16;
    return __builtin_bit_cast(float, u);
}
__device__ __forceinline__ void split_store(float v, unsigned short* hi, unsigned short* lo){
    unsigned short h = f2bf(v);
    *hi = h;
    *lo = f2bf(v - bf2f(h));
}

// ---------------- prep: transpose + split all weights ----------------
__global__ __launch_bounds__(256) void prep_kernel(
    const float* __restrict__ w1, const float* __restrict__ maxv,
    const float* __restrict__ w2, const float* __restrict__ fc1,
    const float* __restrict__ enc, const float* __restrict__ cr,
    const float* __restrict__ ac, const float* __restrict__ aW)
{
    int d = blockIdx.x * 256 + threadIdx.x;
    if (d < 51200){
        int n = d / 800, k = d - n*800;
        int l = k / 25;
        float v = w1[d] / maxv[l];
        int kc = k >> 5, kh = k & 31, ng = n >> 4, r = n & 15;
        int idx = ((kc*4 + ng)*16 + r)*32 + kh;
        g_w1p[idx] = f2bf(v);
        return;
    }
    d -= 51200;
    if (d < 36864){
        int oc = d / 576, k2 = d - oc*576;
        int kxy = k2 >> 6, ic = k2 & 63;
        float v = w2[oc*576 + ic*9 + kxy];
        int kc = k2 >> 6, ks = (k2 >> 5) & 1, kq = k2 & 31, nt = oc >> 4, r = oc & 15;
        int idx = (((kc*2 + ks)*4 + nt)*16 + r)*32 + kq;
        g_w2p[idx] = f2bf(v);                          // conv2 hi-only
        return;
    }
    d -= 36864;
    if (d < 32768){
        int n = d >> 8, kp = d & 255;
        float v = fc1[n*256 + (kp & 63)*4 + (kp >> 6)];
        int idx = ((((n >> 4)*8) + (kp >> 5))*16 + (n & 15))*32 + (kp & 31);
        split_store(v, &g_fc1hi[idx], &g_fc1lo[idx]);
        return;
    }
    d -= 32768;
    if (d < 16384){
        int n = d >> 7, k = d & 127;
        int idx = ((((n >> 4)*4) + (k >> 5))*16 + (n & 15))*32 + (k & 31);
        split_store(enc[d], &g_enchi[idx], &g_enclo[idx]);
        return;
    }
    d -= 16384;
    if (d < 131072){
        int n = d >> 7, k = d & 127;
        int idx = ((((n >> 4)*4) + (k >> 5))*16 + (n & 15))*32 + (k & 31);
        g_crp[idx] = f2bf(cr[d]);                      // critic hi-only (post-tanh damping)
        return;
    }
    d -= 131072;
    if (d < 65536){
        int n = d >> 7, k = d & 127;
        int idx = ((((n >> 4)*4) + (k >> 5))*16 + (n & 15))*32 + (k & 31);
        g_acp[idx] = f2bf(ac[d]);                      // actor hi-only
        return;
    }
    d -= 65536;
    {
        int e = d >> 9, j = d & 511;
        int idx = ((j >> 5)*16 + e)*32 + (j & 31);
        g_qWp[idx] = f2bf(aW[j*16 + e]);               // qW hi-only
    }
}

// ---------------- conv1: M=64 (4 samples/block), grid 2048, 256 threads ----------------
// Wave = n-group owns ALL 4 m-tiles: B read once per block -> per-sample B traffic
// halves (25.6 KB/sample), zero/dedup/scatter per sample also halve. Split-K two-pass
// A-tile [64][424] = 54.3 KB (wtab 32 KB aliased inside) -> 3 blocks/CU (12 waves).
// Per kc: 1 B-load feeds 4 MFMAs (4 independent acc chains across m-tiles).
#define APITCH4 424   // 416 + 8 shorts pad (13 kc pass 0, 12 kc pass 1)
__global__ __launch_bounds__(256, 3) void conv1_kernel(const int* __restrict__ obs,
                                                       const float* __restrict__ b1)
{
    const int b = blockIdx.x;                 // samples b*4 .. b*4+3
    const int tid = threadIdx.x;
    const int wave = tid >> 6, lane = tid & 63;
    const int l15 = lane & 15, lhi = lane >> 4;

    __shared__ char smem[64 * APITCH4 * 2];         // 54,272 B
    int* wtab = (int*)smem;                         // 8192-entry winner table (front-end only)
    unsigned short* sA = (unsigned short*)smem;     // [64][424] A half-tile

    // ---- token load: 4 slots per thread (slots 0..799; <=1 slot per sample per thread) ----
    int   cells[4], xs[4], ys[4], ls[4], ks[4], sis[4];
    float vals[4];
    bool  valids[4], kept[4], act[4];
    #pragma unroll
    for (int u = 0; u < 4; u++){
        const int slot = tid + u*256;
        act[u] = (slot < 800);
        valids[u] = false; kept[u] = false; cells[u] = 0; sis[u] = 0; ks[u] = 0;
        if (act[u]){
            const int si = slot / 200;
            const int k  = slot - si*200;
            const int base = (b*4 + si)*600 + k*3;
            int coord = obs[base], atr = obs[base+1], val = obs[base+2];
            bool valid = (coord != 255) && (atr < 32);
            xs[u] = (coord >> 4) & 15;  ys[u] = coord & 15;  ls[u] = atr;
            cells[u] = valid ? (atr*256 + xs[u]*16 + ys[u]) : 0;   // invalid claims cell 0
            vals[u]  = (float)val;
            valids[u] = valid; sis[u] = si; ks[u] = k;
        }
    }
    // ---- dedup: 4 sequential passes (one per sample); last token-index wins ----
    #pragma unroll
    for (int s = 0; s < 4; s++){
        #pragma unroll
        for (int u = 0; u < 4; u++)
            if (act[u] && sis[u] == s) wtab[cells[u]] = -1;
        __syncthreads();
        #pragma unroll
        for (int u = 0; u < 4; u++)
            if (act[u] && sis[u] == s) atomicMax(&wtab[cells[u]], ks[u]);
        __syncthreads();
        #pragma unroll
        for (int u = 0; u < 4; u++)
            if (act[u] && sis[u] == s) kept[u] = (wtab[cells[u]] == ks[u]);
        __syncthreads();
    }

    // ---- two K-passes over the half-tile; acc chains persist ----
    f32x4 acc[4] = {{0,0,0,0},{0,0,0,0},{0,0,0,0},{0,0,0,0}};
    const unsigned short* Bhp = &g_w1p[wave*512 + l15*32 + lhi*8];

    #pragma unroll
    for (int pass = 0; pass < 2; pass++){
        // zero A half-tile (pass 0 overwrites the dead winner table)
        for (int i = tid; i < 3392; i += 256)
            *(short8*)&sA[i * 8] = short8{0,0,0,0,0,0,0,0};
        __syncthreads();

        // scatter: window-writes whose column falls in this pass's K-range
        #pragma unroll
        for (int u = 0; u < 4; u++){
            if (act[u] && kept[u] && valids[u]){
                const int x3 = xs[u]/3, rx = xs[u] - 3*x3;
                const int y3 = ys[u]/3, ry = ys[u] - 3*y3;
                const unsigned short hv = f2bf(vals[u]);     // exact (integer <= 255)
                #pragma unroll
                for (int d = 0; d < 4; d++){
                    const int dxd = d >> 1, dyd = d & 1;
                    const int ox = x3 - dxd, oy = y3 - dyd;
                    const int wx = rx + 3*dxd, wy = ry + 3*dyd;
                    if (((unsigned)ox <= 3u) && ((unsigned)oy <= 3u) && (wx < 5) && (wy < 5)){
                        const int c = ls[u]*25 + wx*5 + wy;
                        const bool inpass = (pass == 0) ? (c < 416) : (c >= 416);
                        if (inpass)
                            sA[(sis[u]*16 + ox*4 + oy)*APITCH4 + (c - pass*416)] = hv;
                    }
                }
            }
        }
        __syncthreads();

        // K-loop: 1 B-load feeds 4 MFMAs (independent chains per m-tile)
        const int kc0 = (pass == 0) ? 0 : 13;
        const int kc1 = (pass == 0) ? 13 : 25;
        #pragma unroll
        for (int kc = kc0; kc < kc1; kc++){
            const int kl = kc - kc0;
            const short8 bb8 = *(const short8*)&Bhp[kc*2048];
            #pragma unroll
            for (int m = 0; m < 4; m++){
                short8 am = *(const short8*)&sA[(m*16 + l15)*APITCH4 + kl*32 + lhi*8];
                acc[m] = __builtin_amdgcn_mfma_f32_16x16x32_bf16(am, bb8, acc[m], 0, 0, 0);
            }
        }
        if (pass == 0) __syncthreads();   // K-loop reads done before pass-1 re-zero
    }

    const int n = wave*16 + l15;
    const float bb = b1[n];
    #pragma unroll
    for (int m = 0; m < 4; m++){
        #pragma unroll
        for (int j = 0; j < 4; j++){
            const int pos = lhi*4 + j;
            float v = fmaxf(acc[m][j] + bb, 0.f);
            g_ACT1hi[(b*4 + m)*1024 + pos*64 + n] = f2bf(v);
        }
    }
}

// ---------------- tail: conv2+fc1+enc+critic+actor+query+logits fused, 8 waves ------------
// M=16 samples/block, 512 threads (8 waves), grid 512 (2 blocks/CU). LDS 52736 B with
// overlays. conv2/critic/actor/qW weights HI-ONLY.
// Phase 0 single-stages the FULL 16-sample ACT1 tile (32KB hi-only, [16][1032] padded)
// into the dead sX/sH/cb region -> 1 barrier, free-flowing MFMA loads.
__global__ __launch_bounds__(512, 4) void tail_kernel(
    const float* __restrict__ b2,   const float* __restrict__ fc1b,
    const float* __restrict__ encb, const float* __restrict__ crb,
    const float* __restrict__ vw,   const float* __restrict__ vb,
    const float* __restrict__ acb,  const float* __restrict__ emb,
    const float* __restrict__ abias, float* __restrict__ out)
{
    const int r0 = blockIdx.x * 16;
    const int tid = threadIdx.x, wave = tid >> 6, lane = tid & 63;
    const int l15 = lane & 15, lhi = lane >> 4;
    const int coff = l15*32 + lhi*8;                     // coalesced lane offset

    __shared__ char smem[52736];
    unsigned short* sA1h = (unsigned short*)smem;                 // [16][264] 8448 B
    unsigned short* sA1l = (unsigned short*)(smem + 8448);        // 8448 B
    float*          qpart= (float*)smem;                          // [8][16][16] 8192 B (overlays dead sA1)
    unsigned short* sXh  = (unsigned short*)(smem + 16896);       // [16][136] 4352 B
    unsigned short* sXl  = (unsigned short*)(smem + 21248);       // 4352 B
    float* svred = (float*)(smem + 16896);                        // [8][16] 512 B (overlays dead sX)
    float* sq    = (float*)(smem + 17408);                        // [16][17] 1088 B (overlays dead sX)
    float* semb  = (float*)(smem + 18496);                        // [1600] 6400 B (ends 24896 < 25600)
    unsigned short* sHh  = (unsigned short*)(smem + 25600);       // [16][136] 4352 B
    unsigned short* sHl  = (unsigned short*)(smem + 29952);       // 4352 B
    unsigned short* cb   = (unsigned short*)(smem + 34304);       // [8][16][72] 18432 B (ends 52736)
    unsigned short* sACT = (unsigned short*)(smem + 16896);       // [16][1032] 33024 B (phase-0 only,
                                                                  //  overlays dead sX/sH/cb; ends 49920)

    // ---- phase 0: conv2 -> sA1 (LDS). FULL ACT1 tile staged once. ----
    {
        // stage [16][1024] hi-only, row pitch 1032 (pad 8 -> lane-group bank stride 4, 2-way free)
        for (int u = tid; u < 2048; u += 512){
            const int row = u >> 7, c8 = (u & 127) * 8;
            *(short8*)&sACT[row*1032 + c8] = *(const short8*)&g_ACT1hi[(r0 + row)*1024 + c8];
        }
        __syncthreads();

        f32x4 c2acc[2] = {{0,0,0,0},{0,0,0,0}};
        const int tile0 = wave*2,     mt0 = tile0 >> 2, nt0 = tile0 & 3;
        const int tile1 = wave*2 + 1, mt1 = tile1 >> 2, nt1 = tile1 & 3;
        const int row0 = mt0*16 + l15, smp0 = row0 >> 2, px0 = (row0 >> 1) & 1, py0 = row0 & 1;
        const int row1 = mt1*16 + l15, smp1 = row1 >> 2, px1 = (row1 >> 1) & 1, py1 = row1 & 1;
        #pragma unroll
        for (int kc = 0; kc < 9; kc++){
            const int kx = kc / 3, ky = kc - 3*kx;
            const int cell0 = (px0 + kx)*4 + (py0 + ky);
            const int cell1 = (px1 + kx)*4 + (py1 + ky);
            #pragma unroll
            for (int ks = 0; ks < 2; ks++){
                const int kk = ks*32 + lhi*8;
                short8 a0 = *(const short8*)&sACT[smp0*1032 + cell0*64 + kk];
                short8 a1 = *(const short8*)&sACT[smp1*1032 + cell1*64 + kk];
                const short8 b0 = *(const short8*)&g_w2p[((kc*2 + ks)*4 + nt0)*512 + coff];
                const short8 b1 = *(const short8*)&g_w2p[((kc*2 + ks)*4 + nt1)*512 + coff];
                c2acc[0] = __builtin_amdgcn_mfma_f32_16x16x32_bf16(a0, b0, c2acc[0], 0, 0, 0);
                c2acc[1] = __builtin_amdgcn_mfma_f32_16x16x32_bf16(a1, b1, c2acc[1], 0, 0, 0);
            }
        }
        __syncthreads();   // all sACT reads done before sA1/sX region writes below
        #pragma unroll
        for (int wt = 0; wt < 2; wt++){
            const int tile = wave*2 + wt, mt = tile >> 2, nt = tile & 3;
            const int col = nt*16 + l15;
            const float bb = b2[col];
            #pragma unroll
            for (int j = 0; j < 4; j++){
                const int row = mt*16 + lhi*4 + j;           // 0..63 = sample*4 + pos
                float v = fmaxf(c2acc[wt][j] + bb, 0.f);
                unsigned short h = f2bf(v);
                const int ai = (row >> 2)*264 + (row & 3)*64 + col;
                sA1h[ai] = h;
                sA1l[ai] = f2bf(v - bf2f(h));
            }
        }
    }
    __syncthreads();

    // ---- fc1: M=16, N=128 (wave owns n-tile = wave), K=256 -> sX ----
    {
        f32x4 acc = {0,0,0,0};
        const int n = wave*16 + l15;
        #pragma unroll
        for (int kk8 = 0; kk8 < 8; kk8++){
            const int kk = kk8*32 + lhi*8;
            short8 ah = *(const short8*)&sA1h[l15*264 + kk];
            short8 al = *(const short8*)&sA1l[l15*264 + kk];
            const short8 bh = *(const short8*)&g_fc1hi[(wave*8 + kk8)*512 + coff];
            const short8 bl = *(const short8*)&g_fc1lo[(wave*8 + kk8)*512 + coff];
            acc = __builtin_amdgcn_mfma_f32_16x16x32_bf16(ah, bh, acc, 0, 0, 0);
            acc = __builtin_amdgcn_mfma_f32_16x16x32_bf16(al, bh, acc, 0, 0, 0);
            acc = __builtin_amdgcn_mfma_f32_16x16x32_bf16(ah, bl, acc, 0, 0, 0);
        }
        __syncthreads();                      // sA1 reads done before qpart overlays later
        const float bb = fc1b[n];
        #pragma unroll
        for (int j = 0; j < 4; j++){
            const int row = lhi*4 + j;
            float v = fmaxf(acc[j] + bb, 0.f);
            unsigned short h = f2bf(v);
            sXh[row*136 + n] = h;
            sXl[row*136 + n] = f2bf(v - bf2f(h));
        }
    }
    __syncthreads();

    // ---- enc: M=16, N=128 (wave owns n-tile = wave), K=128 -> sH ----
    {
        f32x4 acc = {0,0,0,0};
        const int n = wave*16 + l15;
        #pragma unroll
        for (int kk4 = 0; kk4 < 4; kk4++){
            const int kk = kk4*32 + lhi*8;
            short8 ah = *(const short8*)&sXh[l15*136 + kk];
            short8 al = *(const short8*)&sXl[l15*136 + kk];
            const short8 bh = *(const short8*)&g_enchi[(wave*4 + kk4)*512 + coff];
            const short8 bl = *(const short8*)&g_enclo[(wave*4 + kk4)*512 + coff];
            acc = __builtin_amdgcn_mfma_f32_16x16x32_bf16(ah, bh, acc, 0, 0, 0);
            acc = __builtin_amdgcn_mfma_f32_16x16x32_bf16(al, bh, acc, 0, 0, 0);
            acc = __builtin_amdgcn_mfma_f32_16x16x32_bf16(ah, bl, acc, 0, 0, 0);
        }
        const float bb = encb[n];
        #pragma unroll
        for (int j = 0; j < 4; j++){
            const int row = lhi*4 + j;
            float v = fmaxf(acc[j] + bb, 0.f);
            unsigned short h = f2bf(v);
            sHh[row*136 + n] = h;
            sHl[row*136 + n] = f2bf(v - bf2f(h));
        }
    }
    __syncthreads();                         // sX reads done -> svred/sq/semb may overlay

    // ---- hoist H A-fragments (shared by critic and actor; K=128) ----
    short8 Ah[4], Al[4];
    #pragma unroll
    for (int kk4 = 0; kk4 < 4; kk4++){
        const int kk = kk4*32 + lhi*8;
        Ah[kk4] = *(const short8*)&sHh[l15*136 + kk];
        Al[kk4] = *(const short8*)&sHl[l15*136 + kk];
    }

    // ---- critic: wave owns 128 cols (8 n-tiles); chunks of 4; hi-only B; tanh + vw dot ----
    {
        float vp[4] = {0,0,0,0};
        #pragma unroll
        for (int ntc = 0; ntc < 2; ntc++){
            f32x4 cacc[4];
            #pragma unroll
            for (int q = 0; q < 4; q++) cacc[q] = f32x4{0,0,0,0};
            #pragma unroll
            for (int q = 0; q < 4; q++){
                const int t = wave*8 + ntc*4 + q;        // critic n-tile index
                #pragma unroll
                for (int kk4 = 0; kk4 < 4; kk4++){
                    const short8 bh = *(const short8*)&g_crp[(t*4 + kk4)*512 + coff];
                    cacc[q] = __builtin_amdgcn_mfma_f32_16x16x32_bf16(Ah[kk4], bh, cacc[q], 0, 0, 0);
                    cacc[q] = __builtin_amdgcn_mfma_f32_16x16x32_bf16(Al[kk4], bh, cacc[q], 0, 0, 0);
                }
            }
            #pragma unroll
            for (int q = 0; q < 4; q++){
                const int n = wave*128 + (ntc*4 + q)*16 + l15;
                const float w = vw[n], bb = crb[n];
                #pragma unroll
                for (int j = 0; j < 4; j++)
                    vp[j] += tanhf(cacc[q][j] + bb) * w;
            }
        }
        #pragma unroll
        for (int m = 1; m < 16; m <<= 1)
            #pragma unroll
            for (int j = 0; j < 4; j++) vp[j] += __shfl_xor(vp[j], m, 64);
        if (l15 == 0){
            #pragma unroll
            for (int j = 0; j < 4; j++)
                svred[wave*16 + lhi*4 + j] = vp[j];
        }
    }

    // ---- actor chunk (c = wave, 64 cols, hi-only B + hi-only LDS) + query mini-GEMM ----
    __syncthreads();    // conv2 staging region fully dead; cb reused for actor chunks
    f32x4 qacc = {0,0,0,0};
    {
        const int c = wave;
        f32x4 aacc[4];
        #pragma unroll
        for (int nt = 0; nt < 4; nt++) aacc[nt] = f32x4{0,0,0,0};
        #pragma unroll
        for (int kk4 = 0; kk4 < 4; kk4++){
            #pragma unroll
            for (int nt = 0; nt < 4; nt++){
                const int t = c*4 + nt;                  // actor n-tile index
                const short8 bh = *(const short8*)&g_acp[(t*4 + kk4)*512 + coff];
                aacc[nt] = __builtin_amdgcn_mfma_f32_16x16x32_bf16(Ah[kk4], bh, aacc[nt], 0, 0, 0);
                aacc[nt] = __builtin_amdgcn_mfma_f32_16x16x32_bf16(Al[kk4], bh, aacc[nt], 0, 0, 0);
            }
        }
        // relu + bias -> per-wave LDS chunk [16 rows][64 cols], hi only
        #pragma unroll
        for (int nt = 0; nt < 4; nt++){
            const int col = nt*16 + l15;
            const float bb = acb[c*64 + col];
            #pragma unroll
            for (int j = 0; j < 4; j++){
                const int row = lhi*4 + j;
                cb[(wave*16 + row)*72 + col] = f2bf(fmaxf(aacc[nt][j] + bb, 0.f));
            }
        }
        // query partial over this chunk (K=64), B = qW^T hi-only (coalesced [ck][e][k^])
        #pragma unroll
        for (int kk2 = 0; kk2 < 2; kk2++){
            const int kk = kk2*32 + lhi*8;
            const short8 qbh = *(const short8*)&g_qWp[(c*2 + kk2)*512 + coff];
            const short8 qah = *(const short8*)&cb[(wave*16 + l15)*72 + kk];
            qacc = __builtin_amdgcn_mfma_f32_16x16x32_bf16(qah, qbh, qacc, 0, 0, 0);
        }
    }
    #pragma unroll
    for (int j = 0; j < 4; j++)
        qpart[wave*256 + (lhi*4 + j)*16 + l15] = qacc[j];
    __syncthreads();

    // value out
    if (tid < 16){
        float s = vb[0];
        #pragma unroll
        for (int w = 0; w < 8; w++) s += svred[w*16 + tid];
        out[B_*100 + r0 + tid] = s;
    }
    // finalize q (256 entries)
    if (tid < 256){
        int row = tid >> 4, e = tid & 15;
        float s = 0.f;
        #pragma unroll
        for (int w = 0; w < 8; w++) s += qpart[w*256 + row*16 + e];
        sq[row*17 + e] = tanhf(s);
    }
    for (int k = tid; k < 1600; k += 512) semb[k] = emb[k];
    __syncthreads();
    // logits
    for (int i = tid; i < 1600; i += 512){
        int row = i / 100, a = i - row*100;
        float s = abias[0];
        #pragma unroll
        for (int e = 0; e < 16; e++) s += sq[row*17 + e] * semb[a*16 + e];
        out[(r0 + row)*100 + a] = s;
    }
}

// ---------------- launch ----------------
extern "C" void kernel_launch(void* const* d_in, const int* in_sizes, int n_in,
                              void* d_out, int out_size, void* d_ws, size_t ws_size,
                              hipStream_t stream) {
    const int*   obs   = (const int*)  d_in[0];
    const float* maxv  = (const float*)d_in[1];
    const float* w1    = (const float*)d_in[2];
    const float* b1    = (const float*)d_in[3];
    const float* w2    = (const float*)d_in[4];
    const float* b2    = (const float*)d_in[5];
    const float* fc1w  = (const float*)d_in[6];
    const float* fc1b  = (const float*)d_in[7];
    const float* encw  = (const float*)d_in[8];
    const float* encb  = (const float*)d_in[9];
    const float* crw   = (const float*)d_in[10];
    const float* crb   = (const float*)d_in[11];
    const float* vw    = (const float*)d_in[12];
    const float* vb    = (const float*)d_in[13];
    const float* acw   = (const float*)d_in[14];
    const float* acb   = (const float*)d_in[15];
    const float* emb   = (const float*)d_in[16];
    const float* aW    = (const float*)d_in[17];
    const float* abias = (const float*)d_in[18];
    float* out = (float*)d_out;

    prep_kernel<<<1336, 256, 0, stream>>>(w1, maxv, w2, fc1w, encw, crw, acw, aW);
    conv1_kernel<<<B_/4, 256, 0, stream>>>(obs, b1);
    tail_kernel<<<512, 512, 0, stream>>>(b2, fc1b, encb, crb, vw, vb, acb, emb, abias, out);
}

// Round 36
// 80.988 us; speedup vs baseline: 1.1246x; 1.1246x over previous
//
#include <hip/hip_runtime.h>
#include <math.h>

#define B_ 8192

typedef __attribute__((ext_vector_type(8))) short short8;
typedef __attribute__((ext_vector_type(4))) float f32x4;

// ---------------- persistent device buffers (rewritten every call) ----------------
// ALL GEMM B-matrices stored wave-coalesced: [tile][kkc][r(16)][k^(32)] so one wave
// load = one contiguous 1KB block (lane addr = base + l15*64B + lhi*16B).
__device__ unsigned short g_w1p[51200];                    // conv1 [kc25][ng4][r][k^], /maxv, HI-ONLY
__device__ unsigned short g_w2p[36864];                    // conv2 [kc9*ks2*nt4][r][k^], HI-ONLY
                                                           // (A=ACT1 is hi-only -> B-lo gains <= sqrt2)
__device__ unsigned short g_fc1hi[32768], g_fc1lo[32768];  // fc1   [tn8][kk8][r][k^] (k'=pos*64+oc)
__device__ unsigned short g_enchi[16384], g_enclo[16384];  // enc   [tn8][kk4][r][k^]
__device__ unsigned short g_crp[131072];                   // critic[tn64][kk4][r][k^], HI-ONLY
__device__ unsigned short g_acp[65536];                    // actor [tn32][kk4][r][k^], HI-ONLY
__device__ unsigned short g_qWp[8192];                     // qW^T  [ck16][e16][k^32], HI-ONLY
// activations
__device__ unsigned short g_ACT1hi[8192*1024];             // conv1 out [s][pos*64+oc], HI-ONLY

__device__ __forceinline__ unsigned short f2bf(float v){
    unsigned u = __builtin_bit_cast(unsigned, v);
    unsigned r = (u + 0x7fffu + ((u >> 16) & 1u)) >> 16;   // RN-even (finite inputs)
    return (unsigned short)r;
}
__device__ __forceinline__ float bf2f(unsigned short h){
    unsigned u = ((unsigned)h) << 16;
    return __builtin_bit_cast(float, u);
}
__device__ __forceinline__ void split_store(float v, unsigned short* hi, unsigned short* lo){
    unsigned short h = f2bf(v);
    *hi = h;
    *lo = f2bf(v - bf2f(h));
}

// ---------------- prep: transpose + split all weights ----------------
__global__ __launch_bounds__(256) void prep_kernel(
    const float* __restrict__ w1, const float* __restrict__ maxv,
    const float* __restrict__ w2, const float* __restrict__ fc1,
    const float* __restrict__ enc, const float* __restrict__ cr,
    const float* __restrict__ ac, const float* __restrict__ aW)
{
    int d = blockIdx.x * 256 + threadIdx.x;
    if (d < 51200){
        int n = d / 800, k = d - n*800;
        int l = k / 25;
        float v = w1[d] / maxv[l];
        int kc = k >> 5, kh = k & 31, ng = n >> 4, r = n & 15;
        int idx = ((kc*4 + ng)*16 + r)*32 + kh;
        g_w1p[idx] = f2bf(v);
        return;
    }
    d -= 51200;
    if (d < 36864){
        int oc = d / 576, k2 = d - oc*576;
        int kxy = k2 >> 6, ic = k2 & 63;
        float v = w2[oc*576 + ic*9 + kxy];
        int kc = k2 >> 6, ks = (k2 >> 5) & 1, kq = k2 & 31, nt = oc >> 4, r = oc & 15;
        int idx = (((kc*2 + ks)*4 + nt)*16 + r)*32 + kq;
        g_w2p[idx] = f2bf(v);                          // conv2 hi-only
        return;
    }
    d -= 36864;
    if (d < 32768){
        int n = d >> 8, kp = d & 255;
        float v = fc1[n*256 + (kp & 63)*4 + (kp >> 6)];
        int idx = ((((n >> 4)*8) + (kp >> 5))*16 + (n & 15))*32 + (kp & 31);
        split_store(v, &g_fc1hi[idx], &g_fc1lo[idx]);
        return;
    }
    d -= 32768;
    if (d < 16384){
        int n = d >> 7, k = d & 127;
        int idx = ((((n >> 4)*4) + (k >> 5))*16 + (n & 15))*32 + (k & 31);
        split_store(enc[d], &g_enchi[idx], &g_enclo[idx]);
        return;
    }
    d -= 16384;
    if (d < 131072){
        int n = d >> 7, k = d & 127;
        int idx = ((((n >> 4)*4) + (k >> 5))*16 + (n & 15))*32 + (k & 31);
        g_crp[idx] = f2bf(cr[d]);                      // critic hi-only (post-tanh damping)
        return;
    }
    d -= 131072;
    if (d < 65536){
        int n = d >> 7, k = d & 127;
        int idx = ((((n >> 4)*4) + (k >> 5))*16 + (n & 15))*32 + (k & 31);
        g_acp[idx] = f2bf(ac[d]);                      // actor hi-only
        return;
    }
    d -= 65536;
    {
        int e = d >> 9, j = d & 511;
        int idx = ((j >> 5)*16 + e)*32 + (j & 31);
        g_qWp[idx] = f2bf(aW[j*16 + e]);               // qW hi-only
    }
}

// ---------------- conv1: pack-max dedup + MFMA GEMM (hi-only B, hi-only ACT1 out) ---------
// 256 threads, 4 waves, both m-tiles per B-load (B read once per block; L2-BW-bound).
#define APITCH 808   // 800 + 8 shorts pad
__global__ __launch_bounds__(256) void conv1_kernel(const int* __restrict__ obs,
                                                    const float* __restrict__ b1)
{
    const int b = blockIdx.x;                 // samples b*2, b*2+1
    const int tid = threadIdx.x;
    const int wave = tid >> 6, lane = tid & 63;
    const int l15 = lane & 15, lhi = lane >> 4;

    __shared__ unsigned short sA[32 * APITCH];      // 51712 B; first 32KB doubles as wtab
    int* wtab = (int*)sA;                           // 8192-entry winner table (per pass)

    // ---- early B prefetch (addresses independent of data; flies during dedup) ----
    const unsigned short* Bh = &g_w1p[wave*512 + l15*32 + lhi*8];
    short8 bh0 = *(const short8*)&Bh[0*2048];
    short8 bh1 = *(const short8*)&Bh[1*2048];
    short8 bh2 = *(const short8*)&Bh[2*2048];
    short8 bh3 = *(const short8*)&Bh[3*2048];

    int   cells[2], xs[2], ys[2], ls[2];
    float vals[2];
    bool  valids[2], kept[2];
    #pragma unroll
    for (int u = 0; u < 2; u++){
        const int slot = tid + u*256;
        valids[u] = false; kept[u] = false; cells[u] = 0;
        if (slot < 400){
            const int si = (slot >= 200) ? 1 : 0;
            const int k  = slot - si*200;
            const int base = (b*2 + si)*600 + k*3;
            int coord = obs[base], atr = obs[base+1], val = obs[base+2];
            bool valid = (coord != 255) && (atr < 32);
            xs[u] = (coord >> 4) & 15;  ys[u] = coord & 15;  ls[u] = atr;
            cells[u] = valid ? (atr*256 + xs[u]*16 + ys[u]) : 0;   // invalid claims cell 0
            vals[u]  = (float)val;
            valids[u] = valid;
        }
    }
    // dedup pass A: sample 0
    if (tid < 200) wtab[cells[0]] = -1;
    __syncthreads();
    if (tid < 200) atomicMax(&wtab[cells[0]], tid);
    __syncthreads();
    if (tid < 200) kept[0] = (wtab[cells[0]] == tid);
    __syncthreads();
    // dedup pass B: sample 1
    if (tid >= 200) wtab[cells[0]] = -1;
    if (tid < 144)  wtab[cells[1]] = -1;
    __syncthreads();
    if (tid >= 200) atomicMax(&wtab[cells[0]], tid - 200);
    if (tid < 144)  atomicMax(&wtab[cells[1]], tid + 56);
    __syncthreads();
    if (tid >= 200) kept[0] = (wtab[cells[0]] == tid - 200);
    if (tid < 144)  kept[1] = (wtab[cells[1]] == tid + 56);
    __syncthreads();

    // zero A-tile (overwrites winner table)
    for (int i = tid; i < 4 * APITCH; i += 256)
        *(short8*)&sA[i * 8] = short8{0,0,0,0,0,0,0,0};
    __syncthreads();

    // scatter
    #pragma unroll
    for (int u = 0; u < 2; u++){
        const int slot = tid + u*256;
        if (slot < 400 && kept[u] && valids[u]){
            const int si = (slot >= 200) ? 1 : 0;
            const int x3 = xs[u]/3, rx = xs[u] - 3*x3;
            const int y3 = ys[u]/3, ry = ys[u] - 3*y3;
            const unsigned short hv = f2bf(vals[u]);     // exact (integer <= 255)
            #pragma unroll
            for (int d = 0; d < 4; d++){
                const int dxd = d >> 1, dyd = d & 1;
                const int ox = x3 - dxd, oy = y3 - dyd;
                const int wx = rx + 3*dxd, wy = ry + 3*dyd;
                if (((unsigned)ox <= 3u) && ((unsigned)oy <= 3u) && (wx < 5) && (wy < 5))
                    sA[(si*16 + ox*4 + oy)*APITCH + ls[u]*25 + wx*5 + wy] = hv;
            }
        }
    }
    __syncthreads();

    // MFMA K-loop: kc pairs, even/odd acc chains, 4-deep rolling prefetch, hi-only B
    const int n = wave*16 + l15;
    const unsigned short* A0 = &sA[l15*APITCH + lhi*8];
    const unsigned short* A1 = &sA[(16 + l15)*APITCH + lhi*8];
    f32x4 acc0e = {0,0,0,0}, acc1e = {0,0,0,0};
    f32x4 acc0o = {0,0,0,0}, acc1o = {0,0,0,0};
    #pragma unroll
    for (int kc2 = 0; kc2 < 12; kc2++){              // kc = 2*kc2, 2*kc2+1  (0..23)
        const int kc = kc2*2;
        short8 a0e = *(const short8*)&A0[kc*32];
        short8 a1e = *(const short8*)&A1[kc*32];
        short8 a0o = *(const short8*)&A0[(kc+1)*32];
        short8 a1o = *(const short8*)&A1[(kc+1)*32];
        short8 bhn0, bhn1;
        if (kc2 < 10){
            bhn0 = *(const short8*)&Bh[(kc + 4)*2048];
            bhn1 = *(const short8*)&Bh[(kc + 5)*2048];
        } else if (kc2 == 10){
            bhn0 = *(const short8*)&Bh[24*2048];
        }
        acc0e = __builtin_amdgcn_mfma_f32_16x16x32_bf16(a0e, bh0, acc0e, 0, 0, 0);
        acc1e = __builtin_amdgcn_mfma_f32_16x16x32_bf16(a1e, bh0, acc1e, 0, 0, 0);
        acc0o = __builtin_amdgcn_mfma_f32_16x16x32_bf16(a0o, bh1, acc0o, 0, 0, 0);
        acc1o = __builtin_amdgcn_mfma_f32_16x16x32_bf16(a1o, bh1, acc1o, 0, 0, 0);
        bh0 = bh2; bh1 = bh3; bh2 = bhn0; bh3 = bhn1;
    }
    {   // tail kc = 24 (in bh0 after 12 rotations)
        short8 a0e = *(const short8*)&A0[24*32];
        short8 a1e = *(const short8*)&A1[24*32];
        acc0e = __builtin_amdgcn_mfma_f32_16x16x32_bf16(a0e, bh0, acc0e, 0, 0, 0);
        acc1e = __builtin_amdgcn_mfma_f32_16x16x32_bf16(a1e, bh0, acc1e, 0, 0, 0);
    }
    f32x4 acc0, acc1;
    #pragma unroll
    for (int j = 0; j < 4; j++){ acc0[j] = acc0e[j] + acc0o[j]; acc1[j] = acc1e[j] + acc1o[j]; }

    const float bb = b1[n];
    #pragma unroll
    for (int j = 0; j < 4; j++){
        const int pos = lhi*4 + j;
        float v0 = fmaxf(acc0[j] + bb, 0.f);
        float v1 = fmaxf(acc1[j] + bb, 0.f);
        g_ACT1hi[(b*2    )*1024 + pos*64 + n] = f2bf(v0);
        g_ACT1hi[(b*2 + 1)*1024 + pos*64 + n] = f2bf(v1);
    }
}

// ---------------- tail: conv2+fc1+enc+critic+actor+query+logits fused, 8 waves ------------
// M=16 samples/block, 512 threads (8 waves), grid 512 (2 blocks/CU). LDS 52736 B with
// overlays. conv2/critic/actor/qW weights HI-ONLY.
__global__ __launch_bounds__(512, 4) void tail_kernel(
    const float* __restrict__ b2,   const float* __restrict__ fc1b,
    const float* __restrict__ encb, const float* __restrict__ crb,
    const float* __restrict__ vw,   const float* __restrict__ vb,
    const float* __restrict__ acb,  const float* __restrict__ emb,
    const float* __restrict__ abias, float* __restrict__ out)
{
    const int r0 = blockIdx.x * 16;
    const int tid = threadIdx.x, wave = tid >> 6, lane = tid & 63;
    const int l15 = lane & 15, lhi = lane >> 4;
    const int coff = l15*32 + lhi*8;                     // coalesced lane offset

    __shared__ char smem[52736];
    unsigned short* sA1h = (unsigned short*)smem;                 // [16][264] 8448 B
    unsigned short* sA1l = (unsigned short*)(smem + 8448);        // 8448 B
    float*          qpart= (float*)smem;                          // [8][16][16] 8192 B (overlays dead sA1)
    unsigned short* sXh  = (unsigned short*)(smem + 16896);       // [16][136] 4352 B
    unsigned short* sXl  = (unsigned short*)(smem + 21248);       // 4352 B
    float* svred = (float*)(smem + 16896);                        // [8][16] 512 B (overlays dead sX)
    float* sq    = (float*)(smem + 17408);                        // [16][17] 1088 B (overlays dead sX)
    float* semb  = (float*)(smem + 18496);                        // [1600] 6400 B (ends 24896 < 25600)
    unsigned short* sHh  = (unsigned short*)(smem + 25600);       // [16][136] 4352 B
    unsigned short* sHl  = (unsigned short*)(smem + 29952);       // 4352 B
    unsigned short* cb   = (unsigned short*)(smem + 34304);       // [8][16][72] 18432 B (ends 52736)

    // ---- phase 0: conv2 -> sA1 (LDS). Staging buffer overlays cb region ([64][72] hi). ----
    {
        unsigned short* sAh = cb;
        f32x4 c2acc[2] = {{0,0,0,0},{0,0,0,0}};
        const int srow = tid >> 3, sch8 = (tid & 7) * 8;       // 64 rows x 8 ch-units
        const int spx = (srow >> 1) & 1, spy = srow & 1;
        const int sbase = (r0 + (srow >> 2))*1024;
        for (int kc = 0; kc < 9; kc++){
            const int kx = kc / 3, ky = kc - 3*kx;
            __syncthreads();
            {
                const int cell = (spx + kx)*4 + (spy + ky);
                *(short8*)&sAh[srow*72 + sch8] = *(const short8*)&g_ACT1hi[sbase + cell*64 + sch8];
            }
            __syncthreads();
            #pragma unroll
            for (int wt = 0; wt < 2; wt++){
                const int tile = wave*2 + wt, mt = tile >> 2, nt = tile & 3;
                #pragma unroll
                for (int ks = 0; ks < 2; ks++){
                    const int kk = ks*32 + lhi*8;
                    short8 a = *(const short8*)&sAh[(mt*16 + l15)*72 + kk];
                    const int t = (kc*2 + ks)*4 + nt;
                    const short8 bh = *(const short8*)&g_w2p[t*512 + coff];
                    c2acc[wt] = __builtin_amdgcn_mfma_f32_16x16x32_bf16(a, bh, c2acc[wt], 0, 0, 0);
                }
            }
        }
        __syncthreads();   // staging reads done; sA1 epilogue writes are a separate region
        #pragma unroll
        for (int wt = 0; wt < 2; wt++){
            const int tile = wave*2 + wt, mt = tile >> 2, nt = tile & 3;
            const int col = nt*16 + l15;
            const float bb = b2[col];
            #pragma unroll
            for (int j = 0; j < 4; j++){
                const int row = mt*16 + lhi*4 + j;           // 0..63 = sample*4 + pos
                float v = fmaxf(c2acc[wt][j] + bb, 0.f);
                unsigned short h = f2bf(v);
                const int ai = (row >> 2)*264 + (row & 3)*64 + col;
                sA1h[ai] = h;
                sA1l[ai] = f2bf(v - bf2f(h));
            }
        }
    }
    __syncthreads();

    // ---- fc1: M=16, N=128 (wave owns n-tile = wave), K=256 -> sX ----
    {
        f32x4 acc = {0,0,0,0};
        const int n = wave*16 + l15;
        #pragma unroll
        for (int kk8 = 0; kk8 < 8; kk8++){
            const int kk = kk8*32 + lhi*8;
            short8 ah = *(const short8*)&sA1h[l15*264 + kk];
            short8 al = *(const short8*)&sA1l[l15*264 + kk];
            const short8 bh = *(const short8*)&g_fc1hi[(wave*8 + kk8)*512 + coff];
            const short8 bl = *(const short8*)&g_fc1lo[(wave*8 + kk8)*512 + coff];
            acc = __builtin_amdgcn_mfma_f32_16x16x32_bf16(ah, bh, acc, 0, 0, 0);
            acc = __builtin_amdgcn_mfma_f32_16x16x32_bf16(al, bh, acc, 0, 0, 0);
            acc = __builtin_amdgcn_mfma_f32_16x16x32_bf16(ah, bl, acc, 0, 0, 0);
        }
        __syncthreads();                      // sA1 reads done before qpart overlays later
        const float bb = fc1b[n];
        #pragma unroll
        for (int j = 0; j < 4; j++){
            const int row = lhi*4 + j;
            float v = fmaxf(acc[j] + bb, 0.f);
            unsigned short h = f2bf(v);
            sXh[row*136 + n] = h;
            sXl[row*136 + n] = f2bf(v - bf2f(h));
        }
    }
    __syncthreads();

    // ---- enc: M=16, N=128 (wave owns n-tile = wave), K=128 -> sH ----
    {
        f32x4 acc = {0,0,0,0};
        const int n = wave*16 + l15;
        #pragma unroll
        for (int kk4 = 0; kk4 < 4; kk4++){
            const int kk = kk4*32 + lhi*8;
            short8 ah = *(const short8*)&sXh[l15*136 + kk];
            short8 al = *(const short8*)&sXl[l15*136 + kk];
            const short8 bh = *(const short8*)&g_enchi[(wave*4 + kk4)*512 + coff];
            const short8 bl = *(const short8*)&g_enclo[(wave*4 + kk4)*512 + coff];
            acc = __builtin_amdgcn_mfma_f32_16x16x32_bf16(ah, bh, acc, 0, 0, 0);
            acc = __builtin_amdgcn_mfma_f32_16x16x32_bf16(al, bh, acc, 0, 0, 0);
            acc = __builtin_amdgcn_mfma_f32_16x16x32_bf16(ah, bl, acc, 0, 0, 0);
        }
        const float bb = encb[n];
        #pragma unroll
        for (int j = 0; j < 4; j++){
            const int row = lhi*4 + j;
            float v = fmaxf(acc[j] + bb, 0.f);
            unsigned short h = f2bf(v);
            sHh[row*136 + n] = h;
            sHl[row*136 + n] = f2bf(v - bf2f(h));
        }
    }
    __syncthreads();                         // sX reads done -> svred/sq/semb may overlay

    // ---- hoist H A-fragments (shared by critic and actor; K=128) ----
    short8 Ah[4], Al[4];
    #pragma unroll
    for (int kk4 = 0; kk4 < 4; kk4++){
        const int kk = kk4*32 + lhi*8;
        Ah[kk4] = *(const short8*)&sHh[l15*136 + kk];
        Al[kk4] = *(const short8*)&sHl[l15*136 + kk];
    }

    // ---- critic: wave owns 128 cols (8 n-tiles); chunks of 4; hi-only B; tanh + vw dot ----
    {
        float vp[4] = {0,0,0,0};
        #pragma unroll
        for (int ntc = 0; ntc < 2; ntc++){
            f32x4 cacc[4];
            #pragma unroll
            for (int q = 0; q < 4; q++) cacc[q] = f32x4{0,0,0,0};
            #pragma unroll
            for (int q = 0; q < 4; q++){
                const int t = wave*8 + ntc*4 + q;        // critic n-tile index
                #pragma unroll
                for (int kk4 = 0; kk4 < 4; kk4++){
                    const short8 bh = *(const short8*)&g_crp[(t*4 + kk4)*512 + coff];
                    cacc[q] = __builtin_amdgcn_mfma_f32_16x16x32_bf16(Ah[kk4], bh, cacc[q], 0, 0, 0);
                    cacc[q] = __builtin_amdgcn_mfma_f32_16x16x32_bf16(Al[kk4], bh, cacc[q], 0, 0, 0);
                }
            }
            #pragma unroll
            for (int q = 0; q < 4; q++){
                const int n = wave*128 + (ntc*4 + q)*16 + l15;
                const float w = vw[n], bb = crb[n];
                #pragma unroll
                for (int j = 0; j < 4; j++)
                    vp[j] += tanhf(cacc[q][j] + bb) * w;
            }
        }
        #pragma unroll
        for (int m = 1; m < 16; m <<= 1)
            #pragma unroll
            for (int j = 0; j < 4; j++) vp[j] += __shfl_xor(vp[j], m, 64);
        if (l15 == 0){
            #pragma unroll
            for (int j = 0; j < 4; j++)
                svred[wave*16 + lhi*4 + j] = vp[j];
        }
    }

    // ---- actor chunk (c = wave, 64 cols, hi-only B + hi-only LDS) + query mini-GEMM ----
    __syncthreads();    // conv2 staging region of cb fully dead; reuse for actor chunks
    f32x4 qacc = {0,0,0,0};
    {
        const int c = wave;
        f32x4 aacc[4];
        #pragma unroll
        for (int nt = 0; nt < 4; nt++) aacc[nt] = f32x4{0,0,0,0};
        #pragma unroll
        for (int kk4 = 0; kk4 < 4; kk4++){
            #pragma unroll
            for (int nt = 0; nt < 4; nt++){
                const int t = c*4 + nt;                  // actor n-tile index
                const short8 bh = *(const short8*)&g_acp[(t*4 + kk4)*512 + coff];
                aacc[nt] = __builtin_amdgcn_mfma_f32_16x16x32_bf16(Ah[kk4], bh, aacc[nt], 0, 0, 0);
                aacc[nt] = __builtin_amdgcn_mfma_f32_16x16x32_bf16(Al[kk4], bh, aacc[nt], 0, 0, 0);
            }
        }
        // relu + bias -> per-wave LDS chunk [16 rows][64 cols], hi only
        #pragma unroll
        for (int nt = 0; nt < 4; nt++){
            const int col = nt*16 + l15;
            const float bb = acb[c*64 + col];
            #pragma unroll
            for (int j = 0; j < 4; j++){
                const int row = lhi*4 + j;
                cb[(wave*16 + row)*72 + col] = f2bf(fmaxf(aacc[nt][j] + bb, 0.f));
            }
        }
        // query partial over this chunk (K=64), B = qW^T hi-only (coalesced [ck][e][k^])
        #pragma unroll
        for (int kk2 = 0; kk2 < 2; kk2++){
            const int kk = kk2*32 + lhi*8;
            const short8 qbh = *(const short8*)&g_qWp[(c*2 + kk2)*512 + coff];
            const short8 qah = *(const short8*)&cb[(wave*16 + l15)*72 + kk];
            qacc = __builtin_amdgcn_mfma_f32_16x16x32_bf16(qah, qbh, qacc, 0, 0, 0);
        }
    }
    #pragma unroll
    for (int j = 0; j < 4; j++)
        qpart[wave*256 + (lhi*4 + j)*16 + l15] = qacc[j];
    __syncthreads();

    // value out
    if (tid < 16){
        float s = vb[0];
        #pragma unroll
        for (int w = 0; w < 8; w++) s += svred[w*16 + tid];
        out[B_*100 + r0 + tid] = s;
    }
    // finalize q (256 entries)
    if (tid < 256){
        int row = tid >> 4, e = tid & 15;
        float s = 0.f;
        #pragma unroll
        for (int w = 0; w < 8; w++) s += qpart[w*256 + row*16 + e];
        sq[row*17 + e] = tanhf(s);
    }
    for (int k = tid; k < 1600; k += 512) semb[k] = emb[k];
    __syncthreads();
    // logits
    for (int i = tid; i < 1600; i += 512){
        int row = i / 100, a = i - row*100;
        float s = abias[0];
        #pragma unroll
        for (int e = 0; e < 16; e++) s += sq[row*17 + e] * semb[a*16 + e];
        out[(r0 + row)*100 + a] = s;
    }
}

// ---------------- launch ----------------
extern "C" void kernel_launch(void* const* d_in, const int* in_sizes, int n_in,
                              void* d_out, int out_size, void* d_ws, size_t ws_size,
                              hipStream_t stream) {
    const int*   obs   = (const int*)  d_in[0];
    const float* maxv  = (const float*)d_in[1];
    const float* w1    = (const float*)d_in[2];
    const float* b1    = (const float*)d_in[3];
    const float* w2    = (const float*)d_in[4];
    const float* b2    = (const float*)d_in[5];
    const float* fc1w  = (const float*)d_in[6];
    const float* fc1b  = (const float*)d_in[7];
    const float* encw  = (const float*)d_in[8];
    const float* encb  = (const float*)d_in[9];
    const float* crw   = (const float*)d_in[10];
    const float* crb   = (const float*)d_in[11];
    const float* vw    = (const float*)d_in[12];
    const float* vb    = (const float*)d_in[13];
    const float* acw   = (const float*)d_in[14];
    const float* acb   = (const float*)d_in[15];
    const float* emb   = (const float*)d_in[16];
    const float* aW    = (const float*)d_in[17];
    const float* abias = (const float*)d_in[18];
    float* out = (float*)d_out;

    prep_kernel<<<1336, 256, 0, stream>>>(w1, maxv, w2, fc1w, encw, crw, acw, aW);
    conv1_kernel<<<B_/2, 256, 0, stream>>>(obs, b1);
    tail_kernel<<<512, 512, 0, stream>>>(b2, fc1b, encb, crb, vw, vb, acb, emb, abias, out);
}